// Round 1
// baseline (67.632 us; speedup 1.0000x reference)
//
#include <hip/hip_runtime.h>
#include <hip/hip_bf16.h>

#define NPOS 80
#define VOCABSZ 256
#define HID 128
#define ROWS 32
#define NTHREADS 256
#define HPAD 136   // 128 + 8 pad elements -> 272B row pitch, 16B-aligned

typedef __attribute__((ext_vector_type(8))) short bf16x8;
typedef __attribute__((ext_vector_type(4))) float f32x4;

__device__ __forceinline__ float elu_f(float x) {
    return x > 0.f ? x : expm1f(x);
}

__device__ __forceinline__ unsigned short f2bf(float x) {
    __hip_bfloat16 h = __float2bfloat16(x);  // RNE
    return *reinterpret_cast<unsigned short*>(&h);
}

__global__ __launch_bounds__(NTHREADS, 2)
void topline_fused(const int* __restrict__ msg,
                   const float* __restrict__ W1,
                   const float* __restrict__ b1,
                   const float* __restrict__ W2,
                   const float* __restrict__ b2,
                   float* __restrict__ out)
{
    __shared__ int msg_s[ROWS * NPOS];                 // 10240 B
    __shared__ unsigned short h_s[ROWS * HPAD];        // 8704 B
    __shared__ unsigned short w2t_s[HID * HPAD];       // 34816 B  (w2t_s[n][k] = W2[k][n])

    const int t = threadIdx.x;
    const int block_row0 = blockIdx.x * ROWS;

    // ---- stage message rows (coalesced) ----
    const int* mrow = msg + block_row0 * NPOS;
    #pragma unroll
    for (int i = 0; i < (ROWS * NPOS) / NTHREADS; ++i)
        msg_s[t + i * NTHREADS] = mrow[t + i * NTHREADS];

    // ---- stage W2 transposed to bf16: w2t_s[n][k] = W2[k][n] ----
    const float4* W2v = reinterpret_cast<const float4*>(W2);
    #pragma unroll
    for (int i = 0; i < (HID * HID / 4) / NTHREADS; ++i) {
        int i4 = t + i * NTHREADS;      // float4 index into W2 [k][n]
        int k  = i4 >> 5;               // 32 float4 per k-row
        int n0 = (i4 & 31) * 4;
        float4 w = W2v[i4];
        w2t_s[(n0 + 0) * HPAD + k] = f2bf(w.x);
        w2t_s[(n0 + 1) * HPAD + k] = f2bf(w.y);
        w2t_s[(n0 + 2) * HPAD + k] = f2bf(w.z);
        w2t_s[(n0 + 3) * HPAD + k] = f2bf(w.w);
    }

    __syncthreads();

    // ---- gather phase: 8 rows concurrently, 32 lanes x float4 per row ----
    const int lane32 = t & 31;
    const int slot   = t >> 5;          // 0..7
    const float4* W1v = reinterpret_cast<const float4*>(W1);
    const float4 bv = reinterpret_cast<const float4*>(b1)[lane32];

    for (int rg = 0; rg < ROWS / 8; ++rg) {
        const int row = rg * 8 + slot;
        const int* mr = &msg_s[row * NPOS];
        f32x4 acc = {0.f, 0.f, 0.f, 0.f};
        #pragma unroll 8
        for (int p = 0; p < NPOS; ++p) {
            int c = mr[p];
            int off = (p * VOCABSZ + c) * (HID / 4) + lane32;   // float4 index
            float4 w = W1v[off];
            acc.x += w.x; acc.y += w.y; acc.z += w.z; acc.w += w.w;
        }
        float hx = elu_f(acc.x + bv.x);
        float hy = elu_f(acc.y + bv.y);
        float hz = elu_f(acc.z + bv.z);
        float hw = elu_f(acc.w + bv.w);
        unsigned short* hp = &h_s[row * HPAD + lane32 * 4];
        hp[0] = f2bf(hx); hp[1] = f2bf(hy); hp[2] = f2bf(hz); hp[3] = f2bf(hw);
    }

    __syncthreads();

    // ---- MFMA phase: out[32,128] = elu(h @ W2 + b2) ----
    const int wv   = t >> 6;     // wave 0..3
    const int lane = t & 63;
    const int lrow = lane & 15;
    const int lhi  = lane >> 4;  // 0..3

    for (int nt = wv * 2; nt < wv * 2 + 2; ++nt) {
        #pragma unroll
        for (int mt = 0; mt < 2; ++mt) {
            f32x4 acc = {0.f, 0.f, 0.f, 0.f};
            #pragma unroll
            for (int ks = 0; ks < 4; ++ks) {
                bf16x8 a = *reinterpret_cast<const bf16x8*>(
                    &h_s[(mt * 16 + lrow) * HPAD + ks * 32 + lhi * 8]);
                bf16x8 b = *reinterpret_cast<const bf16x8*>(
                    &w2t_s[(nt * 16 + lrow) * HPAD + ks * 32 + lhi * 8]);
                acc = __builtin_amdgcn_mfma_f32_16x16x32_bf16(a, b, acc, 0, 0, 0);
            }
            int ncol = nt * 16 + lrow;
            float bias = b2[ncol];
            #pragma unroll
            for (int r = 0; r < 4; ++r) {
                int m = mt * 16 + lhi * 4 + r;
                out[(block_row0 + m) * HID + ncol] = elu_f(acc[r] + bias);
            }
        }
    }
}

extern "C" void kernel_launch(void* const* d_in, const int* in_sizes, int n_in,
                              void* d_out, int out_size, void* d_ws, size_t ws_size,
                              hipStream_t stream) {
    const int*   msg = (const int*)d_in[0];
    const float* W1  = (const float*)d_in[1];
    const float* b1  = (const float*)d_in[2];
    const float* W2  = (const float*)d_in[3];
    const float* b2  = (const float*)d_in[4];
    float* out = (float*)d_out;

    int Bn   = in_sizes[0] / NPOS;   // 16384
    int grid = Bn / ROWS;            // 512
    hipLaunchKernelGGL(topline_fused, dim3(grid), dim3(NTHREADS), 0, stream,
                       msg, W1, b1, W2, b2, out);
}

// Round 2
// 41.482 us; speedup vs baseline: 1.6304x; 1.6304x over previous
//
#include <hip/hip_runtime.h>
#include <hip/hip_bf16.h>

#define NPOS 80
#define VOCABSZ 256
#define HID 128
#define ROWS 32
#define NTHREADS 256
#define HPAD 136   // 128 + 8 pad elements -> 272B row pitch, 16B-aligned

typedef __attribute__((ext_vector_type(8))) short bf16x8;
typedef __attribute__((ext_vector_type(4))) float f32x4;

__device__ __forceinline__ float elu_f(float x) {
    return x > 0.f ? x : expm1f(x);
}

__device__ __forceinline__ unsigned short f2bf(float x) {
    __hip_bfloat16 h = __float2bfloat16(x);  // RNE
    return *reinterpret_cast<unsigned short*>(&h);
}

__global__ __launch_bounds__(NTHREADS, 2)
void topline_fused(const int* __restrict__ msg,
                   const float* __restrict__ W1,
                   const float* __restrict__ b1,
                   const float* __restrict__ W2,
                   const float* __restrict__ b2,
                   float* __restrict__ out)
{
    __shared__ int msg_s[ROWS * NPOS];                 // 10240 B
    __shared__ unsigned short h_s[ROWS * HPAD];        // 8704 B
    __shared__ unsigned short w2t_s[HID * HPAD];       // 34816 B  (w2t_s[n][k] = W2[k][n])

    const int t = threadIdx.x;
    const int block_row0 = blockIdx.x * ROWS;

    // ---- stage message rows (coalesced) ----
    const int* mrow = msg + block_row0 * NPOS;
    #pragma unroll
    for (int i = 0; i < (ROWS * NPOS) / NTHREADS; ++i)
        msg_s[t + i * NTHREADS] = mrow[t + i * NTHREADS];

    // ---- stage W2 transposed to bf16: w2t_s[n][k] = W2[k][n] ----
    const float4* W2v = reinterpret_cast<const float4*>(W2);
    #pragma unroll
    for (int i = 0; i < (HID * HID / 4) / NTHREADS; ++i) {
        int i4 = t + i * NTHREADS;      // float4 index into W2 [k][n]
        int k  = i4 >> 5;               // 32 float4 per k-row
        int n0 = (i4 & 31) * 4;
        float4 w = W2v[i4];
        w2t_s[(n0 + 0) * HPAD + k] = f2bf(w.x);
        w2t_s[(n0 + 1) * HPAD + k] = f2bf(w.y);
        w2t_s[(n0 + 2) * HPAD + k] = f2bf(w.z);
        w2t_s[(n0 + 3) * HPAD + k] = f2bf(w.w);
    }

    __syncthreads();

    // ---- gather phase: POSITION-MAJOR sweep for L2 locality ----
    // Each thread owns 4 rows x float4 channels (16 fp32 accumulators).
    // All resident blocks sweep p=0..79 together, so the active W1 slice
    // (256*512B = 131KB per position) stays L2-resident.
    const int lane32 = t & 31;
    const int slot   = t >> 5;          // 0..7 -> rows slot*4 .. slot*4+3
    const int row0   = slot * 4;
    const float4* W1v = reinterpret_cast<const float4*>(W1);

    f32x4 acc[4];
    #pragma unroll
    for (int r = 0; r < 4; ++r) acc[r] = (f32x4){0.f, 0.f, 0.f, 0.f};

    #pragma unroll 2
    for (int p = 0; p < NPOS; ++p) {
        #pragma unroll
        for (int r = 0; r < 4; ++r) {
            int c = msg_s[(row0 + r) * NPOS + p];       // broadcast within slot
            float4 w = W1v[(p * VOCABSZ + c) * (HID / 4) + lane32];
            acc[r].x += w.x; acc[r].y += w.y; acc[r].z += w.z; acc[r].w += w.w;
        }
    }

    const float4 bv = reinterpret_cast<const float4*>(b1)[lane32];
    #pragma unroll
    for (int r = 0; r < 4; ++r) {
        float hx = elu_f(acc[r].x + bv.x);
        float hy = elu_f(acc[r].y + bv.y);
        float hz = elu_f(acc[r].z + bv.z);
        float hw = elu_f(acc[r].w + bv.w);
        unsigned short* hp = &h_s[(row0 + r) * HPAD + lane32 * 4];
        hp[0] = f2bf(hx); hp[1] = f2bf(hy); hp[2] = f2bf(hz); hp[3] = f2bf(hw);
    }

    __syncthreads();

    // ---- MFMA phase: out[32,128] = elu(h @ W2 + b2) ----
    const int wv   = t >> 6;     // wave 0..3
    const int lane = t & 63;
    const int lrow = lane & 15;
    const int lhi  = lane >> 4;  // 0..3

    for (int nt = wv * 2; nt < wv * 2 + 2; ++nt) {
        #pragma unroll
        for (int mt = 0; mt < 2; ++mt) {
            f32x4 acc2 = {0.f, 0.f, 0.f, 0.f};
            #pragma unroll
            for (int ks = 0; ks < 4; ++ks) {
                bf16x8 a = *reinterpret_cast<const bf16x8*>(
                    &h_s[(mt * 16 + lrow) * HPAD + ks * 32 + lhi * 8]);
                bf16x8 b = *reinterpret_cast<const bf16x8*>(
                    &w2t_s[(nt * 16 + lrow) * HPAD + ks * 32 + lhi * 8]);
                acc2 = __builtin_amdgcn_mfma_f32_16x16x32_bf16(a, b, acc2, 0, 0, 0);
            }
            int ncol = nt * 16 + lrow;
            float bias = b2[ncol];
            #pragma unroll
            for (int r = 0; r < 4; ++r) {
                int m = mt * 16 + lhi * 4 + r;
                out[(block_row0 + m) * HID + ncol] = elu_f(acc2[r] + bias);
            }
        }
    }
}

extern "C" void kernel_launch(void* const* d_in, const int* in_sizes, int n_in,
                              void* d_out, int out_size, void* d_ws, size_t ws_size,
                              hipStream_t stream) {
    const int*   msg = (const int*)d_in[0];
    const float* W1  = (const float*)d_in[1];
    const float* b1  = (const float*)d_in[2];
    const float* W2  = (const float*)d_in[3];
    const float* b2  = (const float*)d_in[4];
    float* out = (float*)d_out;

    int Bn   = in_sizes[0] / NPOS;   // 16384
    int grid = Bn / ROWS;            // 512
    hipLaunchKernelGGL(topline_fused, dim3(grid), dim3(NTHREADS), 0, stream,
                       msg, W1, b1, W2, b2, out);
}

// Round 3
// 33.389 us; speedup vs baseline: 2.0256x; 1.2424x over previous
//
#include <hip/hip_runtime.h>
#include <hip/hip_bf16.h>

#define NPOS 80
#define VOCABSZ 256
#define HID 128

typedef __attribute__((ext_vector_type(8))) short bf16x8;
typedef __attribute__((ext_vector_type(4))) float f32x4;
typedef __attribute__((ext_vector_type(4))) unsigned int u32x4;

__device__ __forceinline__ float elu_f(float x) {
    return x > 0.f ? x : expm1f(x);
}

__device__ __forceinline__ unsigned short f2bf(float x) {
    __hip_bfloat16 h = __float2bfloat16(x);  // RNE
    return *reinterpret_cast<unsigned short*>(&h);
}

// ================= prep: W1 fp32->bf16 table + W2 transpose->bf16 =========
#define PREP_W1_BLOCKS 2560   // 20480*128/4 float4 / 256 threads

__global__ __launch_bounds__(256)
void prep_tables(const float* __restrict__ W1, const float* __restrict__ W2,
                 unsigned short* __restrict__ w1b, unsigned short* __restrict__ w2t)
{
    const int b = blockIdx.x;
    const int t = threadIdx.x;
    if (b < PREP_W1_BLOCKS) {
        int idx = b * 256 + t;                       // float4 index
        float4 w = reinterpret_cast<const float4*>(W1)[idx];
        ushort4 o;
        o.x = f2bf(w.x); o.y = f2bf(w.y); o.z = f2bf(w.z); o.w = f2bf(w.w);
        reinterpret_cast<ushort4*>(w1b)[idx] = o;
    } else {
        int j = (b - PREP_W1_BLOCKS) * 256 + t;      // 0..4095
        #pragma unroll
        for (int q = 0; q < 4; ++q) {
            int e = j * 4 + q;                       // 0..16383 over W2 [k][n]
            int k = e >> 7, n = e & 127;
            w2t[n * HID + k] = f2bf(W2[e]);          // w2t[n][k]
        }
    }
}

// ================= main fused kernel (bf16 table path) ====================
#define ROWS16 16
#define NT16 256
#define MPAD 81      // msg row pitch (ints): 81%32=17 -> conflict-free row reads
#define HPAD 136     // h row pitch (ushorts): 272B, 16B-aligned

__global__ __launch_bounds__(NT16, 8)
void topline_bf16(const int* __restrict__ msg,
                  const unsigned short* __restrict__ w1b,
                  const float* __restrict__ b1,
                  const unsigned short* __restrict__ w2t,
                  const float* __restrict__ b2,
                  float* __restrict__ out)
{
    __shared__ int msg_s[ROWS16 * MPAD];             // 5184 B
    __shared__ unsigned short h_s[ROWS16 * HPAD];    // 4352 B

    const int t = threadIdx.x;
    const int block_row0 = blockIdx.x * ROWS16;

    // ---- stage message rows ----
    const int* mrow = msg + block_row0 * NPOS;
    #pragma unroll
    for (int i = 0; i < 5; ++i) {
        int idx = t + i * NT16;                      // < 1280
        int r = idx / NPOS;
        int c = idx - r * NPOS;
        msg_s[r * MPAD + c] = mrow[idx];
    }
    __syncthreads();

    // ---- gather: position-major sweep over bf16 table ----
    // thread (row = t>>4, lane16 = t&15) owns channels lane16*8..+7 of one row
    const int lane16 = t & 15;
    const int row    = t >> 4;
    const int mbase  = row * MPAD;

    float acc[8];
    #pragma unroll
    for (int i = 0; i < 8; ++i) acc[i] = 0.f;

    #pragma unroll 4
    for (int p = 0; p < NPOS; ++p) {
        int c = msg_s[mbase + p];                    // broadcast across 16 lanes
        u32x4 v = *reinterpret_cast<const u32x4*>(
            w1b + ((p * VOCABSZ + c) << 7) + lane16 * 8);
        #pragma unroll
        for (int d = 0; d < 4; ++d) {
            acc[2 * d]     += __uint_as_float(v[d] << 16);        // lo bf16
            acc[2 * d + 1] += __uint_as_float(v[d] & 0xFFFF0000u);// hi bf16
        }
    }

    // ---- bias + elu + store h as bf16 ----
    {
        const float4 ba = reinterpret_cast<const float4*>(b1)[lane16 * 2];
        const float4 bb = reinterpret_cast<const float4*>(b1)[lane16 * 2 + 1];
        unsigned short* hp = &h_s[row * HPAD + lane16 * 8];
        hp[0] = f2bf(elu_f(acc[0] + ba.x));
        hp[1] = f2bf(elu_f(acc[1] + ba.y));
        hp[2] = f2bf(elu_f(acc[2] + ba.z));
        hp[3] = f2bf(elu_f(acc[3] + ba.w));
        hp[4] = f2bf(elu_f(acc[4] + bb.x));
        hp[5] = f2bf(elu_f(acc[5] + bb.y));
        hp[6] = f2bf(elu_f(acc[6] + bb.z));
        hp[7] = f2bf(elu_f(acc[7] + bb.w));
    }
    __syncthreads();

    // ---- MFMA: out[16,128] = elu(h @ W2 + b2); B-frags from global w2t ----
    const int wv   = t >> 6;     // wave 0..3, handles n-tiles 2wv, 2wv+1
    const int lane = t & 63;
    const int lrow = lane & 15;
    const int lhi  = lane >> 4;  // 0..3

    #pragma unroll
    for (int q = 0; q < 2; ++q) {
        int nt = wv * 2 + q;
        f32x4 c4 = {0.f, 0.f, 0.f, 0.f};
        #pragma unroll
        for (int ks = 0; ks < 4; ++ks) {
            bf16x8 a = *reinterpret_cast<const bf16x8*>(
                &h_s[lrow * HPAD + ks * 32 + lhi * 8]);
            bf16x8 bfr = *reinterpret_cast<const bf16x8*>(
                &w2t[(nt * 16 + lrow) * HID + ks * 32 + lhi * 8]);
            c4 = __builtin_amdgcn_mfma_f32_16x16x32_bf16(a, bfr, c4, 0, 0, 0);
        }
        int ncol = nt * 16 + lrow;
        float bias = b2[ncol];
        #pragma unroll
        for (int r = 0; r < 4; ++r)
            out[(block_row0 + lhi * 4 + r) * HID + ncol] = elu_f(c4[r] + bias);
    }
}

// ================= fallback (round-2 kernel, fp32 table) ==================
#define ROWS 32
#define NTHREADS 256

__global__ __launch_bounds__(NTHREADS, 2)
void topline_fused(const int* __restrict__ msg,
                   const float* __restrict__ W1,
                   const float* __restrict__ b1,
                   const float* __restrict__ W2,
                   const float* __restrict__ b2,
                   float* __restrict__ out)
{
    __shared__ int msg_s[ROWS * NPOS];
    __shared__ unsigned short h_s[ROWS * HPAD];
    __shared__ unsigned short w2t_s[HID * HPAD];

    const int t = threadIdx.x;
    const int block_row0 = blockIdx.x * ROWS;

    const int* mrow = msg + block_row0 * NPOS;
    #pragma unroll
    for (int i = 0; i < (ROWS * NPOS) / NTHREADS; ++i)
        msg_s[t + i * NTHREADS] = mrow[t + i * NTHREADS];

    const float4* W2v = reinterpret_cast<const float4*>(W2);
    #pragma unroll
    for (int i = 0; i < (HID * HID / 4) / NTHREADS; ++i) {
        int i4 = t + i * NTHREADS;
        int k  = i4 >> 5;
        int n0 = (i4 & 31) * 4;
        float4 w = W2v[i4];
        w2t_s[(n0 + 0) * HPAD + k] = f2bf(w.x);
        w2t_s[(n0 + 1) * HPAD + k] = f2bf(w.y);
        w2t_s[(n0 + 2) * HPAD + k] = f2bf(w.z);
        w2t_s[(n0 + 3) * HPAD + k] = f2bf(w.w);
    }
    __syncthreads();

    const int lane32 = t & 31;
    const int slot   = t >> 5;
    const int row0   = slot * 4;
    const float4* W1v = reinterpret_cast<const float4*>(W1);

    f32x4 acc[4];
    #pragma unroll
    for (int r = 0; r < 4; ++r) acc[r] = (f32x4){0.f, 0.f, 0.f, 0.f};

    #pragma unroll 2
    for (int p = 0; p < NPOS; ++p) {
        #pragma unroll
        for (int r = 0; r < 4; ++r) {
            int c = msg_s[(row0 + r) * NPOS + p];
            float4 w = W1v[(p * VOCABSZ + c) * (HID / 4) + lane32];
            acc[r].x += w.x; acc[r].y += w.y; acc[r].z += w.z; acc[r].w += w.w;
        }
    }

    const float4 bv = reinterpret_cast<const float4*>(b1)[lane32];
    #pragma unroll
    for (int r = 0; r < 4; ++r) {
        unsigned short* hp = &h_s[(row0 + r) * HPAD + lane32 * 4];
        hp[0] = f2bf(elu_f(acc[r].x + bv.x));
        hp[1] = f2bf(elu_f(acc[r].y + bv.y));
        hp[2] = f2bf(elu_f(acc[r].z + bv.z));
        hp[3] = f2bf(elu_f(acc[r].w + bv.w));
    }
    __syncthreads();

    const int wv   = t >> 6;
    const int lane = t & 63;
    const int lrow = lane & 15;
    const int lhi  = lane >> 4;

    for (int nt = wv * 2; nt < wv * 2 + 2; ++nt) {
        #pragma unroll
        for (int mt = 0; mt < 2; ++mt) {
            f32x4 acc2 = {0.f, 0.f, 0.f, 0.f};
            #pragma unroll
            for (int ks = 0; ks < 4; ++ks) {
                bf16x8 a = *reinterpret_cast<const bf16x8*>(
                    &h_s[(mt * 16 + lrow) * HPAD + ks * 32 + lhi * 8]);
                bf16x8 b = *reinterpret_cast<const bf16x8*>(
                    &w2t_s[(nt * 16 + lrow) * HPAD + ks * 32 + lhi * 8]);
                acc2 = __builtin_amdgcn_mfma_f32_16x16x32_bf16(a, b, acc2, 0, 0, 0);
            }
            int ncol = nt * 16 + lrow;
            float bias = b2[ncol];
            #pragma unroll
            for (int r = 0; r < 4; ++r) {
                int m = mt * 16 + lhi * 4 + r;
                out[(block_row0 + m) * HID + ncol] = elu_f(acc2[r] + bias);
            }
        }
    }
}

// ================= launch =================================================
extern "C" void kernel_launch(void* const* d_in, const int* in_sizes, int n_in,
                              void* d_out, int out_size, void* d_ws, size_t ws_size,
                              hipStream_t stream) {
    const int*   msg = (const int*)d_in[0];
    const float* W1  = (const float*)d_in[1];
    const float* b1  = (const float*)d_in[2];
    const float* W2  = (const float*)d_in[3];
    const float* b2  = (const float*)d_in[4];
    float* out = (float*)d_out;

    int Bn = in_sizes[0] / NPOS;                     // 16384

    const size_t w1b_elems = (size_t)NPOS * VOCABSZ * HID;      // 2,621,440
    const size_t need = (w1b_elems + (size_t)HID * HID) * 2;    // ~5.28 MB

    if (ws_size >= need) {
        unsigned short* w1b = (unsigned short*)d_ws;
        unsigned short* w2t = w1b + w1b_elems;
        hipLaunchKernelGGL(prep_tables, dim3(PREP_W1_BLOCKS + 16), dim3(256), 0, stream,
                           W1, W2, w1b, w2t);
        hipLaunchKernelGGL(topline_bf16, dim3(Bn / ROWS16), dim3(NT16), 0, stream,
                           msg, w1b, b1, w2t, b2, out);
    } else {
        hipLaunchKernelGGL(topline_fused, dim3(Bn / ROWS), dim3(NTHREADS), 0, stream,
                           msg, W1, b1, W2, b2, out);
    }
}